// Round 1
// baseline (72.854 us; speedup 1.0000x reference)
//
#include <hip/hip_runtime.h>

#define HGT 256
#define WID 256
#define NPT 160
#define NBATCH 8
#define ROWS_PER_BLOCK 4

// Kernel 1: per-batch support radius.
// c[b] = 2 * sqrt( max_i min_{j!=i} ||p_i - p_j||^2 ); store 1/c.
__global__ __launch_bounds__(256) void rbf_radius_kernel(const float* __restrict__ cpoint,
                                                         float* __restrict__ inv_c) {
    const int b = blockIdx.x;
    const int tid = threadIdx.x;
    __shared__ float2 pts[NPT];
    __shared__ float red[256];

    if (tid < NPT) {
        pts[tid] = reinterpret_cast<const float2*>(cpoint)[b * NPT + tid];
    }
    __syncthreads();

    float m = 0.0f;  // idle threads contribute 0 (safe: all min-sq-dists >= 0)
    if (tid < NPT) {
        float minv = 1e10f;
        const float2 pi = pts[tid];
        for (int j = 0; j < NPT; ++j) {
            float dx = pi.x - pts[j].x;
            float dy = pi.y - pts[j].y;
            float s = dx * dx + dy * dy;
            s = (j == tid) ? 1e10f : s;  // mask self-distance (reference adds eye*BIG)
            minv = fminf(minv, s);
        }
        m = minv;
    }
    red[tid] = m;
    __syncthreads();
    for (int s = 128; s > 0; s >>= 1) {
        if (tid < s) red[tid] = fmaxf(red[tid], red[tid + s]);
        __syncthreads();
    }
    if (tid == 0) {
        inv_c[b] = 1.0f / (2.0f * sqrtf(red[0]));
    }
}

// Kernel 2: evaluate phi[b][c][h][w] = sum_n wendland(||(x,y)-p_n|| / c_b) * alpha[b][n][c]
// Thread layout: tid = w (full 256-wide row), each thread does ROWS_PER_BLOCK rows.
// dx^2 is shared across the 4 rows (x is fixed per thread).
__global__ __launch_bounds__(256) void rbf_eval_kernel(const float* __restrict__ cpoint,
                                                       const float* __restrict__ alpha,
                                                       const float* __restrict__ inv_c_arr,
                                                       float* __restrict__ out) {
    const int tid = threadIdx.x;
    const int b = blockIdx.x >> 6;        // 64 blocks per batch
    const int blk = blockIdx.x & 63;
    const int h0 = blk * ROWS_PER_BLOCK;  // 64 * 4 = 256 rows
    const float x = (float)tid;

    __shared__ float4 pd[NPT];  // (px, py, a0, a1) packed per point
    if (tid < NPT) {
        float2 p = reinterpret_cast<const float2*>(cpoint)[b * NPT + tid];
        float2 a = reinterpret_cast<const float2*>(alpha)[b * NPT + tid];
        pd[tid] = make_float4(p.x, p.y, a.x, a.y);
    }
    __syncthreads();

    const float inv_c = inv_c_arr[b];

    float acc0[ROWS_PER_BLOCK], acc1[ROWS_PER_BLOCK], yv[ROWS_PER_BLOCK];
#pragma unroll
    for (int k = 0; k < ROWS_PER_BLOCK; ++k) {
        acc0[k] = 0.0f;
        acc1[k] = 0.0f;
        yv[k] = (float)(h0 + k);
    }

#pragma unroll 4
    for (int n = 0; n < NPT; ++n) {
        float4 p = pd[n];          // LDS broadcast read (uniform address)
        float dx = x - p.x;
        float dx2 = dx * dx;
#pragma unroll
        for (int k = 0; k < ROWS_PER_BLOCK; ++k) {
            float dy = yv[k] - p.y;
            float d2 = fmaf(dy, dy, dx2);
            float d = sqrtf(d2) * inv_c;
            float t = 1.0f - d;
            float t2 = t * t;
            float wgt = (t2 * t2) * fmaf(4.0f, d, 1.0f);  // (1-d)^4 * (4d+1)
            wgt = (d < 1.0f) ? wgt : 0.0f;
            acc0[k] = fmaf(wgt, p.z, acc0[k]);
            acc1[k] = fmaf(wgt, p.w, acc1[k]);
        }
    }

    // out[((b*2 + c)*H + h)*W + w], coalesced across tid
#pragma unroll
    for (int k = 0; k < ROWS_PER_BLOCK; ++k) {
        const int h = h0 + k;
        out[((b * 2 + 0) * HGT + h) * WID + tid] = acc0[k];
        out[((b * 2 + 1) * HGT + h) * WID + tid] = acc1[k];
    }
}

extern "C" void kernel_launch(void* const* d_in, const int* in_sizes, int n_in,
                              void* d_out, int out_size, void* d_ws, size_t ws_size,
                              hipStream_t stream) {
    const float* cpoint = (const float*)d_in[0];  // [B, N, 2] f32
    const float* alpha  = (const float*)d_in[1];  // [B, N, 2] f32
    float* inv_c = (float*)d_ws;                  // 8 floats of scratch
    float* out   = (float*)d_out;                 // [B, 2, H, W] f32

    rbf_radius_kernel<<<NBATCH, 256, 0, stream>>>(cpoint, inv_c);
    rbf_eval_kernel<<<NBATCH * (HGT / ROWS_PER_BLOCK), 256, 0, stream>>>(cpoint, alpha, inv_c, out);
}

// Round 3
// 37.686 us; speedup vs baseline: 1.9332x; 1.9332x over previous
//
#include <hip/hip_runtime.h>

#define HGT 256
#define WID 256
#define NPT 160
#define NBATCH 8
#define ROWS_PER_BLOCK 4

// Kernel 1: per-batch support radius.
// c[b] = 2 * sqrt( max_i min_{j!=i} ||p_i - p_j||^2 ); store 1/c.
__global__ __launch_bounds__(256) void rbf_radius_kernel(const float* __restrict__ cpoint,
                                                         float* __restrict__ inv_c) {
    const int b = blockIdx.x;
    const int tid = threadIdx.x;
    __shared__ float2 pts[NPT];
    __shared__ float red[256];

    if (tid < NPT) {
        pts[tid] = reinterpret_cast<const float2*>(cpoint)[b * NPT + tid];
    }
    __syncthreads();

    float m = 0.0f;  // idle threads contribute 0 (safe: all min-sq-dists >= 0)
    if (tid < NPT) {
        float minv = 1e10f;
        const float2 pi = pts[tid];
        for (int j = 0; j < NPT; ++j) {
            float dx = pi.x - pts[j].x;
            float dy = pi.y - pts[j].y;
            float s = dx * dx + dy * dy;
            s = (j == tid) ? 1e10f : s;  // mask self-distance (reference adds eye*BIG)
            minv = fminf(minv, s);
        }
        m = minv;
    }
    red[tid] = m;
    __syncthreads();
    for (int s = 128; s > 0; s >>= 1) {
        if (tid < s) red[tid] = fmaxf(red[tid], red[tid + s]);
        __syncthreads();
    }
    if (tid == 0) {
        inv_c[b] = 1.0f / (2.0f * sqrtf(red[0]));
    }
}

// Kernel 2: phi[b][c][h][w] = sum_n wendland(||(x,y)-p_n|| * inv_c_b) * alpha[b][n][c]
// All coordinates pre-normalized by inv_c. Thread tid = x (256-wide row), 4 rows each.
// Per (wave, point): rect-vs-circle distance test (wave-uniform -> scalar branch)
// skips the whole body when the point's support circle misses the wave's 64x4 footprint.
__global__ __launch_bounds__(256) void rbf_eval_kernel(const float* __restrict__ cpoint,
                                                       const float* __restrict__ alpha,
                                                       const float* __restrict__ inv_c_arr,
                                                       float* __restrict__ out) {
    const int tid = threadIdx.x;
    const int b = blockIdx.x >> 6;        // 64 blocks per batch
    const int blk = blockIdx.x & 63;
    const int h0 = blk * ROWS_PER_BLOCK;  // 64 * 4 = 256 rows

    __shared__ float4 pd[NPT];  // (px*inv_c, py*inv_c, a0, a1) per point
    const float inv_c = inv_c_arr[b];

    if (tid < NPT) {
        float2 p = reinterpret_cast<const float2*>(cpoint)[b * NPT + tid];
        float2 a = reinterpret_cast<const float2*>(alpha)[b * NPT + tid];
        pd[tid] = make_float4(p.x * inv_c, p.y * inv_c, a.x, a.y);
    }
    __syncthreads();

    const float xs = (float)tid * inv_c;          // normalized x of this thread
    // wave footprint in normalized coords: x in [wid*64, wid*64+63], y in [h0, h0+3]
    const int wid = tid >> 6;
    const float wx0 = (float)(wid * 64) * inv_c;
    const float wx1 = (float)(wid * 64 + 63) * inv_c;
    const float wy0 = (float)h0 * inv_c;
    const float wy1 = (float)(h0 + ROWS_PER_BLOCK - 1) * inv_c;

    float acc0[ROWS_PER_BLOCK], acc1[ROWS_PER_BLOCK], ys[ROWS_PER_BLOCK];
#pragma unroll
    for (int k = 0; k < ROWS_PER_BLOCK; ++k) {
        acc0[k] = 0.0f;
        acc1[k] = 0.0f;
        ys[k] = (float)(h0 + k) * inv_c;
    }

    for (int n = 0; n < NPT; ++n) {
        float4 p = pd[n];  // LDS broadcast (uniform address, no conflicts)
        // rect-to-point min distance in normalized units (v_max3 candidates)
        float dxc = fmaxf(fmaxf(wx0 - p.x, p.x - wx1), 0.0f);
        float dyc = fmaxf(fmaxf(wy0 - p.y, p.y - wy1), 0.0f);
        float dmin2 = fmaf(dxc, dxc, dyc * dyc);
        // wave-uniform predicate -> scalar branch, no exec-mask churn
        if (__ballot(dmin2 < 1.0f) != 0ULL) {
            float dx = xs - p.x;
            float dx2 = dx * dx;
#pragma unroll
            for (int k = 0; k < ROWS_PER_BLOCK; ++k) {
                float dy = ys[k] - p.y;
                float d2 = fmaf(dy, dy, dx2);
                float d = __builtin_amdgcn_sqrtf(d2);   // raw v_sqrt_f32, ~1 ULP
                float t = fmaxf(1.0f - d, 0.0f);        // clamp == compact support
                float g = fmaf(4.0f, d, 1.0f);
                float t2 = t * t;
                float wgt = (t2 * t2) * g;              // (1-d)^4 * (4d+1), 0 if d>=1
                acc0[k] = fmaf(wgt, p.z, acc0[k]);
                acc1[k] = fmaf(wgt, p.w, acc1[k]);
            }
        }
    }

    // out[((b*2 + c)*H + h)*W + x], coalesced across tid
#pragma unroll
    for (int k = 0; k < ROWS_PER_BLOCK; ++k) {
        const int h = h0 + k;
        out[((b * 2 + 0) * HGT + h) * WID + tid] = acc0[k];
        out[((b * 2 + 1) * HGT + h) * WID + tid] = acc1[k];
    }
}

extern "C" void kernel_launch(void* const* d_in, const int* in_sizes, int n_in,
                              void* d_out, int out_size, void* d_ws, size_t ws_size,
                              hipStream_t stream) {
    const float* cpoint = (const float*)d_in[0];  // [B, N, 2] f32
    const float* alpha  = (const float*)d_in[1];  // [B, N, 2] f32
    float* inv_c = (float*)d_ws;                  // 8 floats of scratch
    float* out   = (float*)d_out;                 // [B, 2, H, W] f32

    rbf_radius_kernel<<<NBATCH, 256, 0, stream>>>(cpoint, inv_c);
    rbf_eval_kernel<<<NBATCH * (HGT / ROWS_PER_BLOCK), 256, 0, stream>>>(cpoint, alpha, inv_c, out);
}

// Round 6
// 28.786 us; speedup vs baseline: 2.5309x; 1.3092x over previous
//
#include <hip/hip_runtime.h>

#define HGT 256
#define WID 256
#define NPT 160
#define NBATCH 8
#define RPB 4   // rows per thread (block covers 256 cols x 4 rows)

// Fully fused: per-block support-radius recompute (redundant but removes a
// serial kernel dependency), per-wave point-list compaction against the
// wave's 64x4 footprint, then a branch-free unrolled loop over survivors.
__global__ __launch_bounds__(256) void rbf_fused_kernel(const float* __restrict__ cpoint,
                                                        const float* __restrict__ alpha,
                                                        float* __restrict__ out) {
    const int tid = threadIdx.x;
    const int lane = tid & 63;
    const int wv = tid >> 6;              // wave id in block, 0..3
    const int b = blockIdx.x >> 6;        // 64 blocks per batch
    const int blk = blockIdx.x & 63;
    const int h0 = blk * RPB;

    __shared__ float2 spts[NPT];          // raw point coords
    __shared__ float sred[256];
    __shared__ float s_invc;
    __shared__ float4 wl[4][NPT + 4];     // per-wave compacted (px,py,a0,a1), normalized

    const float2* cp2 = reinterpret_cast<const float2*>(cpoint) + b * NPT;
    const float2* al2 = reinterpret_cast<const float2*>(alpha) + b * NPT;

    // ---- Phase 1: support radius (MaxMinPointDist), same math as reference ----
    if (tid < NPT) spts[tid] = cp2[tid];
    __syncthreads();

    float m = 0.0f;  // idle threads contribute 0 (all min-sq-dists >= 0)
    if (tid < NPT) {
        float minv = 1e10f;
        const float2 pi = spts[tid];
#pragma unroll 8
        for (int j = 0; j < NPT; ++j) {
            float dx = pi.x - spts[j].x;
            float dy = pi.y - spts[j].y;
            float s = fmaf(dy, dy, dx * dx);
            s = (j == tid) ? 1e10f : s;   // mask self-distance
            minv = fminf(minv, s);
        }
        m = minv;
    }
    sred[tid] = m;
    __syncthreads();
    for (int s = 128; s > 0; s >>= 1) {
        if (tid < s) sred[tid] = fmaxf(sred[tid], sred[tid + s]);
        __syncthreads();
    }
    if (tid == 0) s_invc = 1.0f / (2.0f * sqrtf(sred[0]));
    __syncthreads();
    const float inv_c = s_invc;

    // ---- Phase 2: per-wave compaction (rect-vs-circle cull, normalized coords) ----
    const float wx0 = (float)(wv * 64) * inv_c;
    const float wx1 = (float)(wv * 64 + 63) * inv_c;
    const float wy0 = (float)h0 * inv_c;
    const float wy1 = (float)(h0 + RPB - 1) * inv_c;

    int cnt = 0;
    for (int r = 0; r < 3; ++r) {
        const int n = r * 64 + lane;
        bool keep = false;
        float4 q;
        if (n < NPT) {
            float2 p = spts[n];           // LDS, stride-8B (2-way aliasing = free)
            float2 a = al2[n];            // global, L1/L2-hot (2.5 KB shared by all)
            q = make_float4(p.x * inv_c, p.y * inv_c, a.x, a.y);
            float dxc = fmaxf(fmaxf(wx0 - q.x, q.x - wx1), 0.0f);
            float dyc = fmaxf(fmaxf(wy0 - q.y, q.y - wy1), 0.0f);
            keep = fmaf(dxc, dxc, dyc * dyc) < 1.0f;  // same float ops as body => safe cull
        }
        const unsigned long long mk = __ballot(keep);
        if (keep) {
            int pre = __popcll(mk & ((1ULL << lane) - 1ULL));
            wl[wv][cnt + pre] = q;
        }
        cnt += __popcll(mk);
    }
    // pad to multiple of 4 with far-away zero-alpha dummies (weight == 0 exactly)
    const int padded = (cnt + 3) & ~3;
    if (lane < padded - cnt) wl[wv][cnt + lane] = make_float4(1e9f, 1e9f, 0.0f, 0.0f);
    // per-wave write->read: compiler inserts lgkmcnt waits; no block barrier needed

    // ---- Phase 3: branch-free accumulate over compacted list ----
    const float xs = (float)tid * inv_c;
    float acc0[RPB], acc1[RPB], ys[RPB];
#pragma unroll
    for (int k = 0; k < RPB; ++k) {
        acc0[k] = 0.0f;
        acc1[k] = 0.0f;
        ys[k] = (float)(h0 + k) * inv_c;
    }

    const float4* wlp = wl[wv];
#define BODY(q)                                                   \
    {                                                             \
        float dx = xs - (q).x;                                    \
        float dx2 = dx * dx;                                      \
        _Pragma("unroll")                                         \
        for (int k = 0; k < RPB; ++k) {                           \
            float dy = ys[k] - (q).y;                             \
            float d2 = fmaf(dy, dy, dx2);                         \
            float d = __builtin_amdgcn_sqrtf(d2);                 \
            float t = fmaxf(1.0f - d, 0.0f);                      \
            float g = fmaf(4.0f, d, 1.0f);                        \
            float t2 = t * t;                                     \
            float wgt = (t2 * t2) * g;                            \
            acc0[k] = fmaf(wgt, (q).z, acc0[k]);                  \
            acc1[k] = fmaf(wgt, (q).w, acc1[k]);                  \
        }                                                         \
    }

    for (int i = 0; i < padded; i += 4) {
        float4 q0 = wlp[i + 0];   // 4 broadcast ds_read_b128 in flight
        float4 q1 = wlp[i + 1];
        float4 q2 = wlp[i + 2];
        float4 q3 = wlp[i + 3];
        BODY(q0);
        BODY(q1);
        BODY(q2);
        BODY(q3);
    }
#undef BODY

    // ---- Output: out[((b*2 + c)*H + h)*W + x], coalesced across tid ----
#pragma unroll
    for (int k = 0; k < RPB; ++k) {
        const int h = h0 + k;
        out[((b * 2 + 0) * HGT + h) * WID + tid] = acc0[k];
        out[((b * 2 + 1) * HGT + h) * WID + tid] = acc1[k];
    }
}

extern "C" void kernel_launch(void* const* d_in, const int* in_sizes, int n_in,
                              void* d_out, int out_size, void* d_ws, size_t ws_size,
                              hipStream_t stream) {
    const float* cpoint = (const float*)d_in[0];  // [B, N, 2] f32
    const float* alpha  = (const float*)d_in[1];  // [B, N, 2] f32
    float* out = (float*)d_out;                   // [B, 2, H, W] f32

    rbf_fused_kernel<<<NBATCH * (HGT / RPB), 256, 0, stream>>>(cpoint, alpha, out);
}